// Round 18
// baseline (102.644 us; speedup 1.0000x reference)
//
#include <hip/hip_runtime.h>
#include <hip/hip_bf16.h>

typedef __attribute__((ext_vector_type(8))) short bf16x8;
typedef __attribute__((ext_vector_type(4))) float f32x4;

#define NCOLP 384                 // padded columns (352 real + 32 zero)
#define STEP_SHORTS (NCOLP * 32)  // 12288 shorts = 24576 B per 32-k step
#define STEP_BYTES 24576
#define SEG_BYTES 6144            // Wpack per-ablk segment: 384 cols * 8k * 2B
#define NSTEP 32
#define BROWS 65536
#define QSZ 32768                 // quarter tile: 64 rows x 512 B bf16

static __device__ __forceinline__ unsigned int bf16rne(float f) {
  unsigned int u = __float_as_uint(f);
  return (u + 0x7FFFu + ((u >> 16) & 1u)) >> 16;
}
static __device__ __forceinline__ unsigned int pack2(float a, float b) {
  return bf16rne(a) | (bf16rne(b) << 16);
}

// Wpack layout: [step][ablk(4)][col(384)][k%8] (bf16), 24576 B/step.
// Column map: [0,100) task0 (e*10+h), [100,200) task1, [200,300) shared,
// [300,340) gates (t*20+g), [340,384) zero pad.
__global__ void ple_prep(const float* __restrict__ Ws, const float* __restrict__ bs,
                         const float* __restrict__ Wt, const float* __restrict__ bt,
                         const float* __restrict__ Wg, const float* __restrict__ bg,
                         unsigned short* __restrict__ Wpack, float* __restrict__ bias) {
  const int n = blockIdx.x;  // 0..383
  const int tid = threadIdx.x;
  const float* src = nullptr;
  int stride = 0;
  float bval = 0.f;
  if (n < 200) {
    int t = n / 100, m = n % 100, e = m / 10, h = m % 10;
    src = Wt + (size_t)(t * 10 + e) * 10240 + h;
    stride = 10;
    bval = bt[(t * 10 + e) * 10 + h];
  } else if (n < 300) {
    int m = n - 200, e = m / 10, h = m % 10;
    src = Ws + (size_t)e * 10240 + h;
    stride = 10;
    bval = bs[e * 10 + h];
  } else if (n < 340) {
    int m = n - 300, t = m / 20, g = m % 20;
    src = Wg + (size_t)t * 20480 + g;
    stride = 20;
    bval = bg[t * 20 + g];
  }
  for (int j = 0; j < 4; j++) {
    int k = tid + j * 256;
    float v = src ? src[(size_t)k * stride] : 0.f;
    Wpack[(size_t)(k >> 5) * STEP_SHORTS + ((k >> 3) & 3) * (NCOLP * 8) + n * 8 +
          (k & 7)] = (unsigned short)bf16rne(v);
  }
  if (tid == 0 && n < 352) bias[n] = bval;
}

// Main: 256 threads = 4 waves, 64 rows/block, 1024 blocks, 2 blocks/CU.
// T14 async-STAGE quarters: per quarter-K, [issue 16 float4 HBM loads for
// q+1 (stay in flight)] -> [compute 8 barrier-free K-steps from buf q&1:
// swizzled ds_read_b128 A + double-banked register B from L2 Wpack] ->
// [pack+ds_write q+1 to the other buf] -> [single barrier]. The ~900cy
// HBM latency and the cvt VALU both hide under compute. Each wave owns a
// 96-col slice (zero B duplication). acc stays AGPR-resident (no dynamic
// indexing anywhere; q-loop fully unrolled).
__global__ __launch_bounds__(256, 2) void ple_main(
    const float* __restrict__ x, const unsigned short* __restrict__ Wpack,
    const float* __restrict__ bias, const float* __restrict__ Wc,
    const float* __restrict__ bc, const float* __restrict__ Wv,
    const float* __restrict__ bv, float* __restrict__ out) {
  __shared__ __align__(16) char smem[2 * QSZ];  // z[16][357] aliases buf0
  float* z = (float*)smem;

  const int tid = threadIdx.x;
  const int l = tid & 63, w = tid >> 6;  // wave w -> cols [w*96, w*96+96)
  const int arow = l & 15, ablk = l >> 4;
  const int rowbase = blockIdx.x * 64;

  const f32x4 fzero = {0.f, 0.f, 0.f, 0.f};
  f32x4 acc[4][6];
#pragma unroll
  for (int i = 0; i < 4; ++i)
#pragma unroll
    for (int j = 0; j < 6; ++j) acc[i][j] = fzero;

  // B fragment base (per-lane 16B from Wpack; k-order matches A frags).
  const char* bbase = (const char*)Wpack + ablk * SEG_BYTES +
                      (w * 96 + arow) * 16;
  bf16x8 bA[6], bB[6];  // double bank, static indexing only

  // Preload B(0).
#pragma unroll
  for (int nt = 0; nt < 6; nt++)
    bA[nt] = *(const bf16x8*)(bbase + nt * 256);

  // Stage mapping (verified R13): srow = w*2 + (l>>5), seg = l&31;
  // per quarter, thread covers rows srow+8j (j=0..7), 32B fp32 each.
  const int srow = w * 2 + (l >> 5);
  const int seg = l & 31;
  const char* xrow =
      (const char*)x + (size_t)(rowbase + srow) * 4096 + seg * 32;

  float4 fq[16];  // in-flight stage quarter (all indices static via unroll)

#define Q_ISSUE(qq)                                                            \
  {                                                                            \
    const char* sb = xrow + (qq)*1024;                                         \
    _Pragma("unroll") for (int j = 0; j < 8; j++) {                            \
      fq[2 * j] = *(const float4*)(sb + (size_t)j * 8 * 4096);                 \
      fq[2 * j + 1] = *(const float4*)(sb + (size_t)j * 8 * 4096 + 16);        \
    }                                                                          \
  }
#define Q_WRITE(qq)                                                            \
  {                                                                            \
    char* buf = smem + ((qq)&1) * QSZ;                                         \
    _Pragma("unroll") for (int j = 0; j < 8; j++) {                            \
      const int row = srow + j * 8;                                            \
      const int segp = (seg & 24) | ((seg & 7) ^ (row & 7));                   \
      *(uint4*)(buf + row * 512 + segp * 16) = make_uint4(                     \
          pack2(fq[2 * j].x, fq[2 * j].y), pack2(fq[2 * j].z, fq[2 * j].w),    \
          pack2(fq[2 * j + 1].x, fq[2 * j + 1].y),                             \
          pack2(fq[2 * j + 1].z, fq[2 * j + 1].w));                            \
    }                                                                          \
  }

  // ---- prologue: stage quarter 0 into buf0 ----
  Q_ISSUE(0)
  __builtin_amdgcn_sched_barrier(0);
  Q_WRITE(0)
  __syncthreads();

#define STEP(kk, bc_, bn_)                                                     \
  {                                                                            \
    const int kn = ((kk) + 1 < NSTEP) ? (kk) + 1 : NSTEP - 1;                  \
    const char* bp = bbase + (size_t)kn * STEP_BYTES;                          \
    _Pragma("unroll") for (int nt = 0; nt < 6; nt++)                           \
        bn_[nt] = *(const bf16x8*)(bp + nt * 256);                             \
    _Pragma("unroll") for (int mf = 0; mf < 4; mf++) {                         \
      const int s = ((kk)&7) * 4 + ablk;                                       \
      const int sgp = (s & 24) | ((s & 7) ^ (arow & 7));                       \
      const bf16x8 av =                                                        \
          *(const bf16x8*)(bufc + (mf * 16 + arow) * 512 + sgp * 16);          \
      _Pragma("unroll") for (int nt = 0; nt < 6; nt++)                         \
          acc[mf][nt] = __builtin_amdgcn_mfma_f32_16x16x32_bf16(               \
              av, bc_[nt], acc[mf][nt], 0, 0, 0);                              \
    }                                                                          \
  }

#pragma unroll
  for (int q = 0; q < 4; ++q) {
    // (a) issue next quarter's 16 HBM loads; they stay in flight under (b)
    if (q < 3) {
      Q_ISSUE(q + 1)
    }
    __builtin_amdgcn_sched_barrier(0);
    // (b) compute 8 K-steps from buf q&1 (barrier-free; B double-banked)
    {
      const char* bufc = smem + (q & 1) * QSZ;
#pragma unroll
      for (int kp = 0; kp < 4; kp++) {
        STEP(q * 8 + 2 * kp, bA, bB)
        STEP(q * 8 + 2 * kp + 1, bB, bA)
      }
    }
    __builtin_amdgcn_sched_barrier(0);
    // (c) pack + write next quarter to the other buf (loads have landed)
    if (q < 3) {
      Q_WRITE(q + 1)
    }
    // (d) one barrier: write(q+1) visible; all waves done reading buf q&1
    __syncthreads();
  }
#undef STEP
#undef Q_ISSUE
#undef Q_WRITE

  // ---- epilogue: 4 phases of 16 rows (z[16][357] aliases buf0).
  // D layout: row = mf*16 + ablk*4 + reg, col = w*96 + nt*16 + arow.
#pragma unroll
  for (int p = 0; p < 4; p++) {
#pragma unroll
    for (int nt = 0; nt < 6; nt++) {
      if (!(w == 3 && nt >= 4)) {  // cols >= 352 are zero pad
#pragma unroll
        for (int r = 0; r < 4; r++)
          z[(ablk * 4 + r) * 357 + w * 96 + nt * 16 + arow] = acc[p][nt][r];
      }
    }
    __syncthreads();
    if (tid < 32) {
      const int t = tid >> 4, r = tid & 15;
      const float* zr = &z[r * 357];
      float gl[20], m = -1e30f;
#pragma unroll
      for (int u = 0; u < 20; u++) {
        gl[u] = zr[300 + t * 20 + u] + bias[300 + t * 20 + u];
        m = fmaxf(m, gl[u]);
      }
      float pr[20], s = 0.f;
#pragma unroll
      for (int u = 0; u < 20; u++) {
        pr[u] = __expf(gl[u] - m);
        s += pr[u];
      }
      const float inv = 1.f / s;
      const float* Wl = t ? Wv : Wc;
      float wl[10];
#pragma unroll
      for (int h = 0; h < 10; h++) wl[h] = Wl[h];
      float accum = 0.f;
#pragma unroll
      for (int u = 0; u < 10; u++) {
        float d = 0.f;
#pragma unroll
        for (int h = 0; h < 10; h++) {
          int c = t * 100 + u * 10 + h;
          d += fmaxf(zr[c] + bias[c], 0.f) * wl[h];
        }
        accum += pr[u] * d;
      }
#pragma unroll
      for (int u = 0; u < 10; u++) {
        float d = 0.f;
#pragma unroll
        for (int h = 0; h < 10; h++) {
          int c = 200 + u * 10 + h;
          d += fmaxf(zr[c] + bias[c], 0.f) * wl[h];
        }
        accum += pr[10 + u] * d;
      }
      float logit = (t ? bv[0] : bc[0]) + accum * inv;
      out[(size_t)t * BROWS + rowbase + p * 16 + r] =
          1.f / (1.f + __expf(-logit));
    }
    __syncthreads();
  }
}

extern "C" void kernel_launch(void* const* d_in, const int* in_sizes, int n_in,
                              void* d_out, int out_size, void* d_ws, size_t ws_size,
                              hipStream_t stream) {
  const float* x = (const float*)d_in[0];
  const float* Ws = (const float*)d_in[3];
  const float* bs = (const float*)d_in[4];
  const float* Wt = (const float*)d_in[5];
  const float* bt = (const float*)d_in[6];
  const float* Wg = (const float*)d_in[7];
  const float* bg = (const float*)d_in[8];
  const float* Wc = (const float*)d_in[9];
  const float* bc = (const float*)d_in[10];
  const float* Wv = (const float*)d_in[11];
  const float* bv = (const float*)d_in[12];
  unsigned short* Wpack = (unsigned short*)d_ws;
  float* bias = (float*)((char*)d_ws + (size_t)NCOLP * 1024 * 2);
  float* out = (float*)d_out;

  hipLaunchKernelGGL(ple_prep, dim3(NCOLP), dim3(256), 0, stream, Ws, bs, Wt, bt,
                     Wg, bg, Wpack, bias);
  hipLaunchKernelGGL(ple_main, dim3(BROWS / 64), dim3(256), 0, stream, x, Wpack,
                     bias, Wc, bc, Wv, bv, out);
}

// Round 19
// 84.883 us; speedup vs baseline: 1.2092x; 1.2092x over previous
//
#include <hip/hip_runtime.h>
#include <hip/hip_bf16.h>

typedef __attribute__((ext_vector_type(8))) short bf16x8;
typedef __attribute__((ext_vector_type(4))) float f32x4;

#define NCOLP 384                 // padded columns (352 real + 32 zero)
#define STEP_SHORTS (NCOLP * 32)  // 12288 shorts = 24576 B per 32-k step
#define STEP_BYTES 24576
#define SEG_BYTES 6144            // Wpack per-ablk segment: 384 cols * 8k * 2B
#define NSTEP 32
#define HSTEP 16
#define BROWS 65536

static __device__ __forceinline__ unsigned int bf16rne(float f) {
  unsigned int u = __float_as_uint(f);
  return (u + 0x7FFFu + ((u >> 16) & 1u)) >> 16;
}
static __device__ __forceinline__ unsigned int pack2(float a, float b) {
  return bf16rne(a) | (bf16rne(b) << 16);
}

// Wpack layout: [step][ablk(4)][col(384)][k%8] (bf16), 24576 B/step.
// Column map: [0,100) task0 (e*10+h), [100,200) task1, [200,300) shared,
// [300,340) gates (t*20+g), [340,384) zero pad.
__global__ void ple_prep(const float* __restrict__ Ws, const float* __restrict__ bs,
                         const float* __restrict__ Wt, const float* __restrict__ bt,
                         const float* __restrict__ Wg, const float* __restrict__ bg,
                         unsigned short* __restrict__ Wpack, float* __restrict__ bias) {
  const int n = blockIdx.x;  // 0..383
  const int tid = threadIdx.x;
  const float* src = nullptr;
  int stride = 0;
  float bval = 0.f;
  if (n < 200) {
    int t = n / 100, m = n % 100, e = m / 10, h = m % 10;
    src = Wt + (size_t)(t * 10 + e) * 10240 + h;
    stride = 10;
    bval = bt[(t * 10 + e) * 10 + h];
  } else if (n < 300) {
    int m = n - 200, e = m / 10, h = m % 10;
    src = Ws + (size_t)e * 10240 + h;
    stride = 10;
    bval = bs[e * 10 + h];
  } else if (n < 340) {
    int m = n - 300, t = m / 20, g = m % 20;
    src = Wg + (size_t)t * 20480 + g;
    stride = 20;
    bval = bg[t * 20 + g];
  }
  for (int j = 0; j < 4; j++) {
    int k = tid + j * 256;
    float v = src ? src[(size_t)k * stride] : 0.f;
    Wpack[(size_t)(k >> 5) * STEP_SHORTS + ((k >> 3) & 3) * (NCOLP * 8) + n * 8 +
          (k & 7)] = (unsigned short)bf16rne(v);
  }
  if (tid == 0 && n < 352) bias[n] = bval;
}

// Main: 256 threads = 4 waves, 64 rows/block, 1024 blocks, 2 blocks/CU.
// R11/R15 phase-split structure + TRIPLE-BANKED B with lead-2 prefetch:
// step i consumes the bank loaded at step i-2, so its vmcnt wait leaves
// ~12 younger loads in flight (~2 K-steps of L2-latency cover) instead of
// double-banking's 1-step lead. Anti-phase h0 block stagger retained.
__global__ __launch_bounds__(256, 2) void ple_main(
    const float* __restrict__ x, const unsigned short* __restrict__ Wpack,
    const float* __restrict__ bias, const float* __restrict__ Wc,
    const float* __restrict__ bc, const float* __restrict__ Wv,
    const float* __restrict__ bv, float* __restrict__ out) {
  // A half-tile: 64 rows x 64 segs(16B bf16, XOR-swizzled) = 65536 B.
  // Epilogue z[32][357] (45.7 KB) aliases it after the final barrier.
  __shared__ __align__(16) char smem[65536];
  float* z = (float*)smem;

  const int tid = threadIdx.x;
  const int l = tid & 63, w = tid >> 6;  // wave w -> cols [w*96, w*96+96)
  const int arow = l & 15, ablk = l >> 4;
  const int rowbase = blockIdx.x * 64;
  const int h0 = (int)(blockIdx.x & 1);  // first half processed (stagger)

  const f32x4 fzero = {0.f, 0.f, 0.f, 0.f};
  f32x4 acc[4][6];
#pragma unroll
  for (int i = 0; i < 4; ++i)
#pragma unroll
    for (int j = 0; j < 6; ++j) acc[i][j] = fzero;

  // B fragment base (per-lane 16B from Wpack; k-order matches A frags).
  const char* bbase = (const char*)Wpack + ablk * SEG_BYTES +
                      (w * 96 + arow) * 16;
  bf16x8 b0[6], b1[6], b2[6];  // triple bank, static indexing only

  // Global step sequence: seq[i] = (h0*16 + i) & 31, i = 0..31.
  // Preload seq[0] -> b0, seq[1] -> b1.
#pragma unroll
  for (int nt = 0; nt < 6; nt++) {
    b0[nt] = *(const bf16x8*)(bbase + (size_t)(((h0 << 4) + 0) & 31) *
                                          STEP_BYTES + nt * 256);
    b1[nt] = *(const bf16x8*)(bbase + (size_t)(((h0 << 4) + 1) & 31) *
                                          STEP_BYTES + nt * 256);
  }

  // STEPX(I, BU, BP): consume bank BU (= seq[I]), prefetch seq[I+2] -> BP.
  // I compile-time; ksl = I & 15 indexes the LDS half-tile.
#define STEPX(I, BU, BP)                                                       \
  {                                                                            \
    const int ipre = ((I) + 2 <= 31) ? (I) + 2 : 31;                           \
    const int kpre = ((h0 << 4) + ipre) & 31;                                  \
    const char* bp = bbase + (size_t)kpre * STEP_BYTES;                        \
    _Pragma("unroll") for (int nt = 0; nt < 6; nt++)                           \
        BP[nt] = *(const bf16x8*)(bp + nt * 256);                              \
    _Pragma("unroll") for (int mf = 0; mf < 4; mf++) {                         \
      const int ksl = (I)&15;                                                  \
      const bf16x8 av = *(const bf16x8*)(smem + (mf * 16 + arow) * 1024 +      \
                                         (((ksl * 4 + ablk) ^ (arow & 7)) *    \
                                          16));                                \
      _Pragma("unroll") for (int nt = 0; nt < 6; nt++)                         \
          acc[mf][nt] = __builtin_amdgcn_mfma_f32_16x16x32_bf16(               \
              av, BU[nt], acc[mf][nt], 0, 0, 0);                               \
    }                                                                          \
  }

#pragma unroll
  for (int hh = 0; hh < 2; ++hh) {
    const int half = h0 ^ hh;
    // ---- stage phase: rows w + 4j (j=0..15); lane l = seg l (8 k) ----
    {
      const char* xb = (const char*)x + (size_t)(rowbase + w) * 4096 +
                       (size_t)half * 2048 + l * 32;
#pragma unroll 4
      for (int j = 0; j < 16; j++) {
        const float4 f0 = *(const float4*)(xb + (size_t)j * 4 * 4096);
        const float4 f1 = *(const float4*)(xb + (size_t)j * 4 * 4096 + 16);
        const int row = w + j * 4;
        char* dst = smem + row * 1024 + ((l ^ (row & 7)) * 16);
        *(uint4*)dst = make_uint4(pack2(f0.x, f0.y), pack2(f0.z, f0.w),
                                  pack2(f1.x, f1.y), pack2(f1.z, f1.w));
      }
    }
    __syncthreads();  // A half-tile visible to all waves

    // ---- compute phase: 16 K-steps, barrier-free, bank residue I%3 ----
    if (hh == 0) {
      STEPX(0, b0, b2)  STEPX(1, b1, b0)  STEPX(2, b2, b1)
      STEPX(3, b0, b2)  STEPX(4, b1, b0)  STEPX(5, b2, b1)
      STEPX(6, b0, b2)  STEPX(7, b1, b0)  STEPX(8, b2, b1)
      STEPX(9, b0, b2)  STEPX(10, b1, b0) STEPX(11, b2, b1)
      STEPX(12, b0, b2) STEPX(13, b1, b0) STEPX(14, b2, b1)
      STEPX(15, b0, b2)
    } else {
      STEPX(16, b1, b0) STEPX(17, b2, b1) STEPX(18, b0, b2)
      STEPX(19, b1, b0) STEPX(20, b2, b1) STEPX(21, b0, b2)
      STEPX(22, b1, b0) STEPX(23, b2, b1) STEPX(24, b0, b2)
      STEPX(25, b1, b0) STEPX(26, b2, b1) STEPX(27, b0, b2)
      STEPX(28, b1, b0) STEPX(29, b2, b1) STEPX(30, b0, b2)
      STEPX(31, b1, b0)
    }
    __syncthreads();  // all reads done before next stage / epilogue reuse
  }
#undef STEPX

  // ---- epilogue: 2 phases of 32 rows. D layout: row=(l>>4)*4+reg, col=l&15.
#pragma unroll
  for (int p = 0; p < 2; p++) {
    __syncthreads();
#pragma unroll
    for (int q = 0; q < 2; q++) {
      const int mf = p * 2 + q;
#pragma unroll
      for (int nt = 0; nt < 6; nt++) {
        if (w == 3 && nt >= 4) continue;  // cols >= 352 are zero pad
#pragma unroll
        for (int r = 0; r < 4; r++)
          z[(q * 16 + ablk * 4 + r) * 357 + w * 96 + nt * 16 + arow] =
              acc[mf][nt][r];
      }
    }
    __syncthreads();
    if (tid < 64) {
      const int t = tid >> 5, r = tid & 31;
      const float* zr = &z[r * 357];
      float gl[20], m = -1e30f;
#pragma unroll
      for (int u = 0; u < 20; u++) {
        gl[u] = zr[300 + t * 20 + u] + bias[300 + t * 20 + u];
        m = fmaxf(m, gl[u]);
      }
      float pr[20], s = 0.f;
#pragma unroll
      for (int u = 0; u < 20; u++) {
        pr[u] = __expf(gl[u] - m);
        s += pr[u];
      }
      const float inv = 1.f / s;
      const float* Wl = t ? Wv : Wc;
      float wl[10];
#pragma unroll
      for (int h = 0; h < 10; h++) wl[h] = Wl[h];
      float accum = 0.f;
#pragma unroll
      for (int u = 0; u < 10; u++) {
        float d = 0.f;
#pragma unroll
        for (int h = 0; h < 10; h++) {
          int c = t * 100 + u * 10 + h;
          d += fmaxf(zr[c] + bias[c], 0.f) * wl[h];
        }
        accum += pr[u] * d;
      }
#pragma unroll
      for (int u = 0; u < 10; u++) {
        float d = 0.f;
#pragma unroll
        for (int h = 0; h < 10; h++) {
          int c = 200 + u * 10 + h;
          d += fmaxf(zr[c] + bias[c], 0.f) * wl[h];
        }
        accum += pr[10 + u] * d;
      }
      float logit = (t ? bv[0] : bc[0]) + accum * inv;
      out[(size_t)t * BROWS + rowbase + p * 32 + r] =
          1.f / (1.f + __expf(-logit));
    }
  }
}

extern "C" void kernel_launch(void* const* d_in, const int* in_sizes, int n_in,
                              void* d_out, int out_size, void* d_ws, size_t ws_size,
                              hipStream_t stream) {
  const float* x = (const float*)d_in[0];
  const float* Ws = (const float*)d_in[3];
  const float* bs = (const float*)d_in[4];
  const float* Wt = (const float*)d_in[5];
  const float* bt = (const float*)d_in[6];
  const float* Wg = (const float*)d_in[7];
  const float* bg = (const float*)d_in[8];
  const float* Wc = (const float*)d_in[9];
  const float* bc = (const float*)d_in[10];
  const float* Wv = (const float*)d_in[11];
  const float* bv = (const float*)d_in[12];
  unsigned short* Wpack = (unsigned short*)d_ws;
  float* bias = (float*)((char*)d_ws + (size_t)NCOLP * 1024 * 2);
  float* out = (float*)d_out;

  hipLaunchKernelGGL(ple_prep, dim3(NCOLP), dim3(256), 0, stream, Ws, bs, Wt, bt,
                     Wg, bg, Wpack, bias);
  hipLaunchKernelGGL(ple_main, dim3(BROWS / 64), dim3(256), 0, stream, x, Wpack,
                     bias, Wc, bc, Wv, bv, out);
}